// Round 14
// baseline (483.879 us; speedup 1.0000x reference)
//
#include <hip/hip_runtime.h>

#define N_NODES 50000
#define N_EDGES 1600000
#define LIN_BLOCKS 782
#define HIST_BLOCKS 1024

typedef __attribute__((ext_vector_type(4))) float f32x4;
typedef __attribute__((ext_vector_type(8))) short bf16x8;
typedef unsigned short u16;

__device__ __forceinline__ float lrelu(float x) { return x >= 0.f ? x : 0.01f * x; }

__device__ __forceinline__ u16 f2bf(float f) {
    union { float f; unsigned u; } v; v.f = f;
    unsigned u = v.u;
    u += 0x7fffu + ((u >> 16) & 1u);
    return (u16)(u >> 16);
}

__device__ __forceinline__ float bf2f(u16 v) {
    union { unsigned u; float f; } x; x.u = ((unsigned)v) << 16; return x.f;
}

__device__ __forceinline__ bf16x8 cvt8(float4 a, float4 b) {
    bf16x8 r;
    r[0] = (short)f2bf(a.x); r[1] = (short)f2bf(a.y);
    r[2] = (short)f2bf(a.z); r[3] = (short)f2bf(a.w);
    r[4] = (short)f2bf(b.x); r[5] = (short)f2bf(b.y);
    r[6] = (short)f2bf(b.z); r[7] = (short)f2bf(b.w);
    return r;
}

// ---------------------------------------------------------------------------
// k_prep: fragment-ordered bf16 weight tables + hist (deg pre-zeroed by
// hipMemsetAsync). Wf layout [kstep][nf][lane][8].
// ---------------------------------------------------------------------------
__launch_bounds__(256)
__global__ void k_prep(const float* __restrict__ W1,
                       const float* __restrict__ W2a, const float* __restrict__ W2b,
                       const float* __restrict__ W3a, const float* __restrict__ W3b,
                       u16* __restrict__ wf1, u16* __restrict__ wf2, u16* __restrict__ wf3,
                       const int* __restrict__ ei, int* __restrict__ deg)
{
    const int b = blockIdx.x;
    if (b < 1024) {
        int i = b * 256 + threadIdx.x;
        int e = i & 7, lane = (i >> 3) & 63, nf = (i >> 9) & 7, ks = i >> 12;
        int n = nf * 16 + (lane & 15);
        int k = ks * 32 + 8 * (lane >> 4) + e;
        wf1[i] = f2bf(W1[(size_t)n * 2048 + k]);
    } else if (b < 1088) {
        int i = (b - 1024) * 256 + threadIdx.x;
        int e = i & 7, lane = (i >> 3) & 63, nf = (i >> 9) & 7, ks = i >> 12;
        int n = nf * 16 + (lane & 15);
        int k = ks * 32 + 8 * (lane >> 4) + e;
        float v = (n < 64) ? W2a[(size_t)n * 128 + k] : W2b[(size_t)(n - 64) * 128 + k];
        wf2[i] = f2bf(v);
    } else if (b < 1104) {
        int i = (b - 1088) * 256 + threadIdx.x;
        int e = i & 7, lane = (i >> 3) & 63, nf = (i >> 9) & 3, ks = i >> 11;
        int n = nf * 16 + (lane & 15);
        int k = ks * 32 + 8 * (lane >> 4) + e;
        float v = (n < 32) ? W3a[(size_t)n * 64 + k] : W3b[(size_t)(n - 32) * 64 + k];
        wf3[i] = f2bf(v);
    } else {
        for (int e = (b - 1104) * 256 + threadIdx.x; e < N_EDGES; e += HIST_BLOCKS * 256)
            atomicAdd(deg + ei[N_EDGES + e], 1);
    }
}

// ---------------------------------------------------------------------------
// k_scan_all: single-block CSR offset scan (replaces scan1+scan2p+scan3).
// 256 threads x 196-elem chunks: per-thread sum -> block scan -> prefix write.
// ---------------------------------------------------------------------------
__launch_bounds__(256)
__global__ void k_scan_all(const int* __restrict__ deg, int* __restrict__ ro,
                           int* __restrict__ cur)
{
    __shared__ int sm[256];
    const int tid = threadIdx.x;
    const int CH = 196;                 // 256*196 = 50176 >= N_NODES
    const int base = tid * CH;

    int sum = 0;
    for (int i = 0; i < CH; i++) {
        int idx = base + i;
        sum += (idx < N_NODES) ? deg[idx] : 0;
    }
    sm[tid] = sum;
    __syncthreads();
#pragma unroll
    for (int off = 1; off < 256; off <<= 1) {
        int v = (tid >= off) ? sm[tid - off] : 0;
        __syncthreads();
        sm[tid] += v;
        __syncthreads();
    }
    int run = (tid > 0) ? sm[tid - 1] : 0;   // exclusive prefix of this chunk
    if (tid == 0) ro[0] = 0;
    for (int i = 0; i < CH; i++) {
        int idx = base + i;
        if (idx < N_NODES) {
            int d = deg[idx];
            cur[idx] = run;
            run += d;
            ro[idx + 1] = run;
        }
    }
}

// ---------------------------------------------------------------------------
// k_linf: FUSED  h1 = lrelu(x @ lin1_w.T + b) -> t1(bf16)/acc1(f32) ; +fill.
// EXACT best-measured (361.4us) configuration — untouched.
// ---------------------------------------------------------------------------
__device__ __forceinline__ void compute_step(const char* slot, int lane, int wave,
                                             f32x4 acc[2][4])
{
    const int lrow = lane & 15;
    const int k16 = lane >> 4;
    const int rs = wave >> 1;                    // row strip (32 rows)
    const int ch = wave & 1;                     // col half (nf base ch*4)

    bf16x8 af[2];
#pragma unroll
    for (int st = 0; st < 2; st++) {
        const int row = rs * 32 + st * 16 + lrow;
        af[st] = *(const bf16x8*)(slot + row * 64 + ((k16 ^ (row & 3)) << 4));
    }
    bf16x8 bf[4];
#pragma unroll
    for (int j = 0; j < 4; j++)
        bf[j] = *(const bf16x8*)(slot + 4096 + (ch * 4 + j) * 1024 + lane * 16);

    __builtin_amdgcn_s_setprio(1);
#pragma unroll
    for (int st = 0; st < 2; st++)
#pragma unroll
        for (int j = 0; j < 4; j++)
            acc[st][j] = __builtin_amdgcn_mfma_f32_16x16x32_bf16(af[st], bf[j], acc[st][j], 0, 0, 0);
    __builtin_amdgcn_s_setprio(0);
}

__launch_bounds__(256, 4)
__global__ void k_linf(const float* __restrict__ X, const u16* __restrict__ Wf1,
                       const u16* __restrict__ Wf2,
                       const float* __restrict__ Bv, const float* __restrict__ brel,
                       u16* __restrict__ t1, float* __restrict__ acc1,
                       const int* __restrict__ ei, int* __restrict__ cur,
                       int* __restrict__ csr)
{
    __shared__ __align__(16) char lds[2][12288];

    const int t = threadIdx.x, wave = t >> 6, lane = t & 63;
    const int lrow = lane & 15, lgrp = lane >> 4;
    const int m0 = blockIdx.x * 64;

    // staging geometry: thread t stages row=t>>2, k-chunk kq=t&3 (8 elems)
    const int arow_l = t >> 2, kq = t & 3;
    int grow = m0 + arow_l; if (grow >= N_NODES) grow = N_NODES - 1;
    const float4* ap = (const float4*)(X + (size_t)grow * 2048);   // + s*8 + kq*2
    const bf16x8* bp = (const bf16x8*)Wf1;                          // + s*512 + t*2
    const int awr = arow_l * 64 + ((kq ^ (arow_l & 3)) << 4);
    const int bwr = 4096 + t * 32;

    f32x4 acc[2][4];
#pragma unroll
    for (int st = 0; st < 2; st++)
#pragma unroll
        for (int j = 0; j < 4; j++) acc[st][j] = (f32x4)0.f;

    // prologue: s=0 (c), s=1 (n); write s=0 into slot0
    float4 cA0 = ap[kq * 2], cA1 = ap[kq * 2 + 1];
    bf16x8 cB0 = bp[t * 2], cB1 = bp[t * 2 + 1];
    float4 nA0 = ap[8 + kq * 2], nA1 = ap[8 + kq * 2 + 1];
    bf16x8 nB0 = bp[512 + t * 2], nB1 = bp[512 + t * 2 + 1];
    *(bf16x8*)(lds[0] + awr) = cvt8(cA0, cA1);
    *(bf16x8*)(lds[0] + bwr) = cB0;
    *(bf16x8*)(lds[0] + bwr + 16) = cB1;
    asm volatile("s_waitcnt lgkmcnt(0)" ::: "memory");
    __builtin_amdgcn_s_barrier();
    __builtin_amdgcn_sched_barrier(0);

#pragma unroll 2
    for (int s = 0; s < 62; s++) {
        // issue loads for stage s+2 (stay in flight across compute+write)
        float4 fA0 = ap[(s + 2) * 8 + kq * 2], fA1 = ap[(s + 2) * 8 + kq * 2 + 1];
        bf16x8 fB0 = bp[(s + 2) * 512 + t * 2], fB1 = bp[(s + 2) * 512 + t * 2 + 1];

        compute_step(lds[s & 1], lane, wave, acc);
        __builtin_amdgcn_s_barrier();                 // all waves done reading slot s&1
        __builtin_amdgcn_sched_barrier(0);

        char* wslot = lds[(s + 1) & 1];
        *(bf16x8*)(wslot + awr) = cvt8(nA0, nA1);
        *(bf16x8*)(wslot + bwr) = nB0;
        *(bf16x8*)(wslot + bwr + 16) = nB1;
        asm volatile("s_waitcnt lgkmcnt(0)" ::: "memory");
        __builtin_amdgcn_s_barrier();                 // slot (s+1)&1 now readable
        __builtin_amdgcn_sched_barrier(0);

        nA0 = fA0; nA1 = fA1; nB0 = fB0; nB1 = fB1;
    }
    // peeled tail: s=62 (write s=63), s=63
    compute_step(lds[0], lane, wave, acc);
    __builtin_amdgcn_s_barrier();
    __builtin_amdgcn_sched_barrier(0);
    *(bf16x8*)(lds[1] + awr) = cvt8(nA0, nA1);
    *(bf16x8*)(lds[1] + bwr) = nB0;
    *(bf16x8*)(lds[1] + bwr + 16) = nB1;
    asm volatile("s_waitcnt lgkmcnt(0)" ::: "memory");
    __builtin_amdgcn_s_barrier();
    __builtin_amdgcn_sched_barrier(0);
    compute_step(lds[1], lane, wave, acc);
    __builtin_amdgcn_s_barrier();     // slots dead after this; hl overlays lds
    __builtin_amdgcn_sched_barrier(0);

    // ---- fused dual GEMM epilogue ----
    u16* hl = (u16*)&lds[0][0];
    {
        const int rs = wave >> 1, ch = wave & 1;
#pragma unroll
        for (int st = 0; st < 2; st++) {
#pragma unroll
            for (int j = 0; j < 4; j++) {
                const int col = ch * 64 + j * 16 + lrow;
                const float bias = Bv[col];
#pragma unroll
                for (int r = 0; r < 4; r++) {
                    const int row = rs * 32 + st * 16 + lgrp * 4 + r;
                    hl[row * 128 + (((col >> 3) ^ (row & 7)) << 3) + (col & 7)] =
                        f2bf(lrelu(acc[st][j][r] + bias));
                }
            }
        }
    }
    asm volatile("s_waitcnt lgkmcnt(0)" ::: "memory");
    __builtin_amdgcn_s_barrier();
    __builtin_amdgcn_sched_barrier(0);

    // dual GEMM: wave handles rows wave*16..+16, all 8 nf (K=128)
    bf16x8 af2[4];
    {
        const int row = wave * 16 + lrow;
#pragma unroll
        for (int ks = 0; ks < 4; ks++) {
            const int chunk = ((ks << 2) + lgrp) ^ (row & 7);
            af2[ks] = *(const bf16x8*)(hl + row * 128 + (chunk << 3));
        }
    }
    f32x4 dacc[8];
#pragma unroll
    for (int i = 0; i < 8; i++) dacc[i] = (f32x4)0.f;
    const u16* bp2 = Wf2 + lane * 8;
#pragma unroll
    for (int ks = 0; ks < 4; ks++) {
#pragma unroll
        for (int nf = 0; nf < 8; nf++) {
            bf16x8 bf = *(const bf16x8*)(bp2 + ks * 4096 + nf * 512);
            dacc[nf] = __builtin_amdgcn_mfma_f32_16x16x32_bf16(af2[ks], bf, dacc[nf], 0, 0, 0);
        }
    }

    const int rbase = m0 + wave * 16 + lgrp * 4;
#pragma unroll
    for (int nf = 0; nf < 8; nf++) {
        const int col = nf * 16 + lrow;
#pragma unroll
        for (int r = 0; r < 4; r++) {
            const int row = rbase + r;
            if (row < N_NODES) {
                if (col < 64) t1[(size_t)row * 64 + col] = f2bf(dacc[nf][r]);
                else          acc1[(size_t)row * 64 + (col - 64)] = dacc[nf][r] + brel[col - 64];
            }
        }
    }

    // ---- CSR fill tail (hidden in block-retirement tail) ----
    for (int e = blockIdx.x * 256 + t; e < N_EDGES; e += LIN_BLOCKS * 256) {
        const int dst = ei[N_EDGES + e];
        const int p = atomicAdd(cur + dst, 1);
        csr[p] = ei[e];
    }
}

// ---------------------------------------------------------------------------
// k_dualf2: t2(bf16)/acc2(f32) from lrelu(acc1)  (K=64, N=64)
// ---------------------------------------------------------------------------
__launch_bounds__(256, 2)
__global__ void k_dualf2(const float* __restrict__ A, const u16* __restrict__ Wf,
                         const float* __restrict__ brel,
                         u16* __restrict__ t2, float* __restrict__ acc2)
{
    const int t = threadIdx.x, wave = t >> 6, lane = t & 63;
    const int lrow = lane & 15, lgrp = lane >> 4;
    const int arow = blockIdx.x * 64 + wave * 16 + lrow;
    const float* ap = A + (size_t)(arow < N_NODES ? arow : 0) * 64 + 8 * lgrp;
    const u16* bp = Wf + lane * 8;

    float4 a00 = *(const float4*)(ap + 0);
    float4 a01 = *(const float4*)(ap + 4);
    float4 a10 = *(const float4*)(ap + 32);
    float4 a11 = *(const float4*)(ap + 36);

    f32x4 acc[4];
#pragma unroll
    for (int i = 0; i < 4; i++) acc[i] = (f32x4)0.f;

    a00.x = lrelu(a00.x); a00.y = lrelu(a00.y); a00.z = lrelu(a00.z); a00.w = lrelu(a00.w);
    a01.x = lrelu(a01.x); a01.y = lrelu(a01.y); a01.z = lrelu(a01.z); a01.w = lrelu(a01.w);
    bf16x8 af0 = cvt8(a00, a01);
    a10.x = lrelu(a10.x); a10.y = lrelu(a10.y); a10.z = lrelu(a10.z); a10.w = lrelu(a10.w);
    a11.x = lrelu(a11.x); a11.y = lrelu(a11.y); a11.z = lrelu(a11.z); a11.w = lrelu(a11.w);
    bf16x8 af1 = cvt8(a10, a11);

#pragma unroll
    for (int nf = 0; nf < 4; nf++) {
        bf16x8 b0 = *(const bf16x8*)(bp + nf * 512);
        bf16x8 b1 = *(const bf16x8*)(bp + 2048 + nf * 512);
        acc[nf] = __builtin_amdgcn_mfma_f32_16x16x32_bf16(af0, b0, acc[nf], 0, 0, 0);
        acc[nf] = __builtin_amdgcn_mfma_f32_16x16x32_bf16(af1, b1, acc[nf], 0, 0, 0);
    }

    const int rbase = blockIdx.x * 64 + wave * 16 + lgrp * 4;
#pragma unroll
    for (int nf = 0; nf < 4; nf++) {
        const int col = nf * 16 + lrow;
#pragma unroll
        for (int r = 0; r < 4; r++) {
            const int row = rbase + r;
            if (row < N_NODES) {
                if (col < 32) t2[(size_t)row * 32 + col] = f2bf(acc[nf][r]);
                else          acc2[(size_t)row * 32 + (col - 32)] = acc[nf][r] + brel[col - 32];
            }
        }
    }
}

// ---------------------------------------------------------------------------
// k_gather64: acc1[n] += sum over in-edges of t1(bf16)[src]; wave/node
// ---------------------------------------------------------------------------
__launch_bounds__(256)
__global__ void k_gather64(const int* __restrict__ ro, const int* __restrict__ csr,
                           const u16* __restrict__ t, float* __restrict__ acc)
{
    const int wid = (blockIdx.x << 2) | (threadIdx.x >> 6);
    if (wid >= N_NODES) return;
    const int lane = threadIdx.x & 63;
    const int s = ro[wid], e = ro[wid + 1];
    float a = acc[(size_t)wid * 64 + lane];
    int i = s;
    for (; i + 8 <= e; i += 8) {
        int s0 = csr[i], s1 = csr[i + 1], s2 = csr[i + 2], s3 = csr[i + 3];
        int s4 = csr[i + 4], s5 = csr[i + 5], s6 = csr[i + 6], s7 = csr[i + 7];
        u16 v0 = t[(size_t)s0 * 64 + lane], v1 = t[(size_t)s1 * 64 + lane];
        u16 v2 = t[(size_t)s2 * 64 + lane], v3 = t[(size_t)s3 * 64 + lane];
        u16 v4 = t[(size_t)s4 * 64 + lane], v5 = t[(size_t)s5 * 64 + lane];
        u16 v6 = t[(size_t)s6 * 64 + lane], v7 = t[(size_t)s7 * 64 + lane];
        a += bf2f(v0); a += bf2f(v1); a += bf2f(v2); a += bf2f(v3);
        a += bf2f(v4); a += bf2f(v5); a += bf2f(v6); a += bf2f(v7);
    }
    for (; i < e; ++i) a += bf2f(t[(size_t)csr[i] * 64 + lane]);
    acc[(size_t)wid * 64 + lane] = a;
}

// ---------------------------------------------------------------------------
// k_gpos: fused gather32 + lrelu + pos GEMV
// ---------------------------------------------------------------------------
__launch_bounds__(256)
__global__ void k_gpos(const int* __restrict__ ro, const int* __restrict__ csr,
                       const u16* __restrict__ t, const float* __restrict__ acc2,
                       const float* __restrict__ PW, const float* __restrict__ PB,
                       float* __restrict__ out)
{
    const int wid = (blockIdx.x << 2) | (threadIdx.x >> 6);
    if (wid >= N_NODES) return;
    const int lane = threadIdx.x & 63;
    const int half = lane >> 5, f = lane & 31;
    const int s = ro[wid], e = ro[wid + 1];
    float a = 0.f;
    int i = s;
    for (; i + 8 <= e; i += 8) {
        int s0 = csr[i + half], s1 = csr[i + 2 + half];
        int s2 = csr[i + 4 + half], s3 = csr[i + 6 + half];
        u16 v0 = t[(size_t)s0 * 32 + f], v1 = t[(size_t)s1 * 32 + f];
        u16 v2 = t[(size_t)s2 * 32 + f], v3 = t[(size_t)s3 * 32 + f];
        a += bf2f(v0); a += bf2f(v1); a += bf2f(v2); a += bf2f(v3);
    }
    for (; i < e; i += 2) {
        int idx = i + half;
        if (idx < e) a += bf2f(t[(size_t)csr[idx] * 32 + f]);
    }
    a += __shfl_xor(a, 32, 64);

    float v = lrelu(acc2[(size_t)wid * 32 + f] + a);
    float p0 = v * PW[f], p1 = v * PW[32 + f], p2 = v * PW[64 + f];
#pragma unroll
    for (int off = 16; off >= 1; off >>= 1) {
        p0 += __shfl_xor(p0, off, 64);
        p1 += __shfl_xor(p1, off, 64);
        p2 += __shfl_xor(p2, off, 64);
    }
    if (lane == 0) {
        out[(size_t)wid * 3 + 0] = p0 + PB[0];
        out[(size_t)wid * 3 + 1] = p1 + PB[1];
        out[(size_t)wid * 3 + 2] = p2 + PB[2];
    }
}

// ---------------------------------------------------------------------------
extern "C" void kernel_launch(void* const* d_in, const int* in_sizes, int n_in,
                              void* d_out, int out_size, void* d_ws, size_t ws_size,
                              hipStream_t stream)
{
    const float* x        = (const float*)d_in[0];
    const int*   ei       = (const int*)d_in[1];
    const float* lin1_w   = (const float*)d_in[2];
    const float* lin1_b   = (const float*)d_in[3];
    const float* c1_wrel  = (const float*)d_in[4];
    const float* c1_brel  = (const float*)d_in[5];
    const float* c1_wroot = (const float*)d_in[6];
    const float* c4_wrel  = (const float*)d_in[7];
    const float* c4_brel  = (const float*)d_in[8];
    const float* c4_wroot = (const float*)d_in[9];
    const float* pos_w    = (const float*)d_in[10];
    const float* pos_b    = (const float*)d_in[11];
    float* out = (float*)d_out;

    char* base = (char*)d_ws;
    u16*   t1b  = (u16*)base;                        // [N][64] bf16 = 6.4 MB
    float* acc1 = (float*)(base + 6400000);          // [N][64] f32  = 12.8 MB
    u16*   t2b  = (u16*)(base + 19200000);           // [N][32] bf16 = 3.2 MB
    float* acc2 = (float*)(base + 22400000);         // [N][32] f32  = 6.4 MB
    u16*   wf1  = (u16*)(base + 28800000);           // 512 KB
    u16*   wf2  = wf1 + 262144;                      // 32 KB
    u16*   wf3  = wf2 + 16384;                       // 8 KB
    int*   ibase = (int*)(wf3 + 4096);
    const int NPAD = ((N_NODES + 255) / 256) * 256;  // 50176
    int* deg  = ibase;
    int* ro   = deg  + NPAD;
    int* cur  = ro   + NPAD;
    int* csr  = cur  + NPAD;

    // deg = 0, then tables + hist together
    hipMemsetAsync(deg, 0, (size_t)NPAD * sizeof(int), stream);
    hipLaunchKernelGGL(k_prep, dim3(1104 + HIST_BLOCKS), dim3(256), 0, stream,
                       lin1_w, c1_wrel, c1_wroot, c4_wrel, c4_wroot,
                       wf1, wf2, wf3, ei, deg);
    // single-block scan -> ro, cur
    hipLaunchKernelGGL(k_scan_all, dim3(1), dim3(256), 0, stream, deg, ro, cur);

    // fused: h1(in-LDS) -> t1/acc1 ; + CSR fill tail
    hipLaunchKernelGGL(k_linf, dim3(LIN_BLOCKS), dim3(256), 0, stream,
                       x, wf1, wf2, lin1_b, c1_brel, t1b, acc1, ei, cur, csr);
    // acc1 += gather(t1)
    hipLaunchKernelGGL(k_gather64, dim3((N_NODES + 3) / 4), dim3(256), 0, stream,
                       ro, csr, t1b, acc1);
    // t2/acc2
    hipLaunchKernelGGL(k_dualf2, dim3((N_NODES + 63) / 64), dim3(256), 0, stream,
                       acc1, wf3, c4_brel, t2b, acc2);
    // out = lrelu(acc2 + gather(t2)) @ pos_w.T + pos_b
    hipLaunchKernelGGL(k_gpos, dim3((N_NODES + 3) / 4), dim3(256), 0, stream,
                       ro, csr, t2b, acc2, pos_w, pos_b, out);
}

// Round 15
// 412.719 us; speedup vs baseline: 1.1724x; 1.1724x over previous
//
#include <hip/hip_runtime.h>

#define N_NODES 50000
#define N_EDGES 1600000

typedef __attribute__((ext_vector_type(4))) float f32x4;
typedef __attribute__((ext_vector_type(8))) short bf16x8;
typedef unsigned short u16;

__device__ __forceinline__ float lrelu(float x) { return x >= 0.f ? x : 0.01f * x; }

__device__ __forceinline__ u16 f2bf(float f) {
    union { float f; unsigned u; } v; v.f = f;
    unsigned u = v.u;
    u += 0x7fffu + ((u >> 16) & 1u);
    return (u16)(u >> 16);
}

__device__ __forceinline__ float bf2f(u16 v) {
    union { unsigned u; float f; } x; x.u = ((unsigned)v) << 16; return x.f;
}

__device__ __forceinline__ bf16x8 cvt8(float4 a, float4 b) {
    bf16x8 r;
    r[0] = (short)f2bf(a.x); r[1] = (short)f2bf(a.y);
    r[2] = (short)f2bf(a.z); r[3] = (short)f2bf(a.w);
    r[4] = (short)f2bf(b.x); r[5] = (short)f2bf(b.y);
    r[6] = (short)f2bf(b.z); r[7] = (short)f2bf(b.w);
    return r;
}

// ---------------------------------------------------------------------------
// k_prep: fragment-ordered bf16 weight tables + deg zeroing.
// Wf layout [kstep][nf][lane][8].
// ---------------------------------------------------------------------------
__launch_bounds__(256)
__global__ void k_prep(const float* __restrict__ W1,
                       const float* __restrict__ W2a, const float* __restrict__ W2b,
                       const float* __restrict__ W3a, const float* __restrict__ W3b,
                       u16* __restrict__ wf1, u16* __restrict__ wf2, u16* __restrict__ wf3,
                       int* __restrict__ deg)
{
    const int b = blockIdx.x;
    if (b < 1024) {
        int i = b * 256 + threadIdx.x;
        int e = i & 7, lane = (i >> 3) & 63, nf = (i >> 9) & 7, ks = i >> 12;
        int n = nf * 16 + (lane & 15);
        int k = ks * 32 + 8 * (lane >> 4) + e;
        wf1[i] = f2bf(W1[(size_t)n * 2048 + k]);
    } else if (b < 1088) {
        int i = (b - 1024) * 256 + threadIdx.x;
        int e = i & 7, lane = (i >> 3) & 63, nf = (i >> 9) & 7, ks = i >> 12;
        int n = nf * 16 + (lane & 15);
        int k = ks * 32 + 8 * (lane >> 4) + e;
        float v = (n < 64) ? W2a[(size_t)n * 128 + k] : W2b[(size_t)(n - 64) * 128 + k];
        wf2[i] = f2bf(v);
    } else if (b < 1104) {
        int i = (b - 1088) * 256 + threadIdx.x;
        int e = i & 7, lane = (i >> 3) & 63, nf = (i >> 9) & 3, ks = i >> 11;
        int n = nf * 16 + (lane & 15);
        int k = ks * 32 + 8 * (lane >> 4) + e;
        float v = (n < 32) ? W3a[(size_t)n * 64 + k] : W3b[(size_t)(n - 32) * 64 + k];
        wf3[i] = f2bf(v);
    } else {
        int i = (b - 1104) * 256 + threadIdx.x;
        if (i < N_NODES) deg[i] = 0;
    }
}

__launch_bounds__(256)
__global__ void k_hist(const int* __restrict__ ei, int* __restrict__ deg)
{
    const int stride = gridDim.x * 256;
    for (int e = blockIdx.x * 256 + threadIdx.x; e < N_EDGES; e += stride)
        atomicAdd(deg + ei[N_EDGES + e], 1);
}

// ---------------------------------------------------------------------------
// k_linf: FUSED  h1 = lrelu(x @ lin1_w.T + b) -> t1(bf16)/acc1(f32).
// Best-measured configuration (361.4 us total): BM=64, 256 threads,
// 2x2 wave layout, 2-slot ping-pong (slot 12KB = A 4KB bf16 + B 8KB),
// 2-stage reg lookahead, raw s_barrier + lgkmcnt only, (256,4) -> all 782
// blocks resident.
// ---------------------------------------------------------------------------
__device__ __forceinline__ void compute_step(const char* slot, int lane, int wave,
                                             f32x4 acc[2][4])
{
    const int lrow = lane & 15;
    const int k16 = lane >> 4;
    const int rs = wave >> 1;                    // row strip (32 rows)
    const int ch = wave & 1;                     // col half (nf base ch*4)

    bf16x8 af[2];
#pragma unroll
    for (int st = 0; st < 2; st++) {
        const int row = rs * 32 + st * 16 + lrow;
        af[st] = *(const bf16x8*)(slot + row * 64 + ((k16 ^ (row & 3)) << 4));
    }
    bf16x8 bf[4];
#pragma unroll
    for (int j = 0; j < 4; j++)
        bf[j] = *(const bf16x8*)(slot + 4096 + (ch * 4 + j) * 1024 + lane * 16);

    __builtin_amdgcn_s_setprio(1);
#pragma unroll
    for (int st = 0; st < 2; st++)
#pragma unroll
        for (int j = 0; j < 4; j++)
            acc[st][j] = __builtin_amdgcn_mfma_f32_16x16x32_bf16(af[st], bf[j], acc[st][j], 0, 0, 0);
    __builtin_amdgcn_s_setprio(0);
}

__launch_bounds__(256, 4)
__global__ void k_linf(const float* __restrict__ X, const u16* __restrict__ Wf1,
                       const u16* __restrict__ Wf2,
                       const float* __restrict__ Bv, const float* __restrict__ brel,
                       u16* __restrict__ t1, float* __restrict__ acc1)
{
    __shared__ __align__(16) char lds[2][12288];

    const int t = threadIdx.x, wave = t >> 6, lane = t & 63;
    const int lrow = lane & 15, lgrp = lane >> 4;
    const int m0 = blockIdx.x * 64;

    // staging geometry: thread t stages row=t>>2, k-chunk kq=t&3 (8 elems)
    const int arow_l = t >> 2, kq = t & 3;
    int grow = m0 + arow_l; if (grow >= N_NODES) grow = N_NODES - 1;
    const float4* ap = (const float4*)(X + (size_t)grow * 2048);   // + s*8 + kq*2
    const bf16x8* bp = (const bf16x8*)Wf1;                          // + s*512 + t*2
    const int awr = arow_l * 64 + ((kq ^ (arow_l & 3)) << 4);
    const int bwr = 4096 + t * 32;

    f32x4 acc[2][4];
#pragma unroll
    for (int st = 0; st < 2; st++)
#pragma unroll
        for (int j = 0; j < 4; j++) acc[st][j] = (f32x4)0.f;

    // prologue: s=0 (c), s=1 (n); write s=0 into slot0
    float4 cA0 = ap[kq * 2], cA1 = ap[kq * 2 + 1];
    bf16x8 cB0 = bp[t * 2], cB1 = bp[t * 2 + 1];
    float4 nA0 = ap[8 + kq * 2], nA1 = ap[8 + kq * 2 + 1];
    bf16x8 nB0 = bp[512 + t * 2], nB1 = bp[512 + t * 2 + 1];
    *(bf16x8*)(lds[0] + awr) = cvt8(cA0, cA1);
    *(bf16x8*)(lds[0] + bwr) = cB0;
    *(bf16x8*)(lds[0] + bwr + 16) = cB1;
    asm volatile("s_waitcnt lgkmcnt(0)" ::: "memory");
    __builtin_amdgcn_s_barrier();
    __builtin_amdgcn_sched_barrier(0);

#pragma unroll 2
    for (int s = 0; s < 62; s++) {
        // issue loads for stage s+2 (stay in flight across compute+write)
        float4 fA0 = ap[(s + 2) * 8 + kq * 2], fA1 = ap[(s + 2) * 8 + kq * 2 + 1];
        bf16x8 fB0 = bp[(s + 2) * 512 + t * 2], fB1 = bp[(s + 2) * 512 + t * 2 + 1];

        compute_step(lds[s & 1], lane, wave, acc);
        __builtin_amdgcn_s_barrier();                 // all waves done reading slot s&1
        __builtin_amdgcn_sched_barrier(0);

        char* wslot = lds[(s + 1) & 1];
        *(bf16x8*)(wslot + awr) = cvt8(nA0, nA1);
        *(bf16x8*)(wslot + bwr) = nB0;
        *(bf16x8*)(wslot + bwr + 16) = nB1;
        asm volatile("s_waitcnt lgkmcnt(0)" ::: "memory");
        __builtin_amdgcn_s_barrier();                 // slot (s+1)&1 now readable
        __builtin_amdgcn_sched_barrier(0);

        nA0 = fA0; nA1 = fA1; nB0 = fB0; nB1 = fB1;
    }
    // peeled tail: s=62 (write s=63), s=63
    compute_step(lds[0], lane, wave, acc);
    __builtin_amdgcn_s_barrier();
    __builtin_amdgcn_sched_barrier(0);
    *(bf16x8*)(lds[1] + awr) = cvt8(nA0, nA1);
    *(bf16x8*)(lds[1] + bwr) = nB0;
    *(bf16x8*)(lds[1] + bwr + 16) = nB1;
    asm volatile("s_waitcnt lgkmcnt(0)" ::: "memory");
    __builtin_amdgcn_s_barrier();
    __builtin_amdgcn_sched_barrier(0);
    compute_step(lds[1], lane, wave, acc);
    __builtin_amdgcn_s_barrier();     // slots dead after this; hl overlays lds
    __builtin_amdgcn_sched_barrier(0);

    // ---- fused dual GEMM epilogue ----
    // hl[64][128] bf16 (16 KB overlaying slots), chunk-XOR swizzle:
    // h[row][col] -> u16 idx row*128 + ((col>>3)^(row&7))*8 + (col&7)
    u16* hl = (u16*)&lds[0][0];
    {
        const int rs = wave >> 1, ch = wave & 1;
#pragma unroll
        for (int st = 0; st < 2; st++) {
#pragma unroll
            for (int j = 0; j < 4; j++) {
                const int col = ch * 64 + j * 16 + lrow;
                const float bias = Bv[col];
#pragma unroll
                for (int r = 0; r < 4; r++) {
                    const int row = rs * 32 + st * 16 + lgrp * 4 + r;
                    hl[row * 128 + (((col >> 3) ^ (row & 7)) << 3) + (col & 7)] =
                        f2bf(lrelu(acc[st][j][r] + bias));
                }
            }
        }
    }
    asm volatile("s_waitcnt lgkmcnt(0)" ::: "memory");
    __builtin_amdgcn_s_barrier();
    __builtin_amdgcn_sched_barrier(0);

    // dual GEMM: wave handles rows wave*16..+16, all 8 nf (K=128)
    bf16x8 af2[4];
    {
        const int row = wave * 16 + lrow;
#pragma unroll
        for (int ks = 0; ks < 4; ks++) {
            const int chunk = ((ks << 2) + lgrp) ^ (row & 7);
            af2[ks] = *(const bf16x8*)(hl + row * 128 + (chunk << 3));
        }
    }
    f32x4 dacc[8];
#pragma unroll
    for (int i = 0; i < 8; i++) dacc[i] = (f32x4)0.f;
    const u16* bp2 = Wf2 + lane * 8;
#pragma unroll
    for (int ks = 0; ks < 4; ks++) {
#pragma unroll
        for (int nf = 0; nf < 8; nf++) {
            bf16x8 bf = *(const bf16x8*)(bp2 + ks * 4096 + nf * 512);
            dacc[nf] = __builtin_amdgcn_mfma_f32_16x16x32_bf16(af2[ks], bf, dacc[nf], 0, 0, 0);
        }
    }

    const int rbase = m0 + wave * 16 + lgrp * 4;
#pragma unroll
    for (int nf = 0; nf < 8; nf++) {
        const int col = nf * 16 + lrow;
#pragma unroll
        for (int r = 0; r < 4; r++) {
            const int row = rbase + r;
            if (row < N_NODES) {
                if (col < 64) t1[(size_t)row * 64 + col] = f2bf(dacc[nf][r]);
                else          acc1[(size_t)row * 64 + (col - 64)] = dacc[nf][r] + brel[col - 64];
            }
        }
    }
}

// ---------------------------------------------------------------------------
// k_dualf2: t2(bf16)/acc2(f32) from lrelu(acc1)  (K=64, N=64)
// ---------------------------------------------------------------------------
__launch_bounds__(256, 2)
__global__ void k_dualf2(const float* __restrict__ A, const u16* __restrict__ Wf,
                         const float* __restrict__ brel,
                         u16* __restrict__ t2, float* __restrict__ acc2)
{
    const int t = threadIdx.x, wave = t >> 6, lane = t & 63;
    const int lrow = lane & 15, lgrp = lane >> 4;
    const int arow = blockIdx.x * 64 + wave * 16 + lrow;
    const float* ap = A + (size_t)(arow < N_NODES ? arow : 0) * 64 + 8 * lgrp;
    const u16* bp = Wf + lane * 8;

    float4 a00 = *(const float4*)(ap + 0);
    float4 a01 = *(const float4*)(ap + 4);
    float4 a10 = *(const float4*)(ap + 32);
    float4 a11 = *(const float4*)(ap + 36);

    f32x4 acc[4];
#pragma unroll
    for (int i = 0; i < 4; i++) acc[i] = (f32x4)0.f;

    a00.x = lrelu(a00.x); a00.y = lrelu(a00.y); a00.z = lrelu(a00.z); a00.w = lrelu(a00.w);
    a01.x = lrelu(a01.x); a01.y = lrelu(a01.y); a01.z = lrelu(a01.z); a01.w = lrelu(a01.w);
    bf16x8 af0 = cvt8(a00, a01);
    a10.x = lrelu(a10.x); a10.y = lrelu(a10.y); a10.z = lrelu(a10.z); a10.w = lrelu(a10.w);
    a11.x = lrelu(a11.x); a11.y = lrelu(a11.y); a11.z = lrelu(a11.z); a11.w = lrelu(a11.w);
    bf16x8 af1 = cvt8(a10, a11);

#pragma unroll
    for (int nf = 0; nf < 4; nf++) {
        bf16x8 b0 = *(const bf16x8*)(bp + nf * 512);
        bf16x8 b1 = *(const bf16x8*)(bp + 2048 + nf * 512);
        acc[nf] = __builtin_amdgcn_mfma_f32_16x16x32_bf16(af0, b0, acc[nf], 0, 0, 0);
        acc[nf] = __builtin_amdgcn_mfma_f32_16x16x32_bf16(af1, b1, acc[nf], 0, 0, 0);
    }

    const int rbase = blockIdx.x * 64 + wave * 16 + lgrp * 4;
#pragma unroll
    for (int nf = 0; nf < 4; nf++) {
        const int col = nf * 16 + lrow;
#pragma unroll
        for (int r = 0; r < 4; r++) {
            const int row = rbase + r;
            if (row < N_NODES) {
                if (col < 32) t2[(size_t)row * 32 + col] = f2bf(acc[nf][r]);
                else          acc2[(size_t)row * 32 + (col - 32)] = acc[nf][r] + brel[col - 32];
            }
        }
    }
}

// ---------------------------------------------------------------------------
// scans (CSR offsets) + fill
// ---------------------------------------------------------------------------
__launch_bounds__(256)
__global__ void k_scan1(const int* __restrict__ deg, int* __restrict__ tmp,
                        int* __restrict__ bsum)
{
    __shared__ int sm[256];
    const int tid = threadIdx.x;
    const int i = blockIdx.x * 256 + tid;
    int d = (i < N_NODES) ? deg[i] : 0;
    sm[tid] = d;
    __syncthreads();
#pragma unroll
    for (int off = 1; off < 256; off <<= 1) {
        int v = (tid >= off) ? sm[tid - off] : 0;
        __syncthreads();
        sm[tid] += v;
        __syncthreads();
    }
    if (i < N_NODES) tmp[i] = sm[tid];
    if (tid == 255) bsum[blockIdx.x] = sm[255];
}

__launch_bounds__(256)
__global__ void k_scan2p(const int* __restrict__ bsum, int* __restrict__ boff, int nb)
{
    __shared__ int sm[256];
    const int tid = threadIdx.x;
    int v = (tid < nb) ? bsum[tid] : 0;
    sm[tid] = v;
    __syncthreads();
#pragma unroll
    for (int off = 1; off < 256; off <<= 1) {
        int u = (tid >= off) ? sm[tid - off] : 0;
        __syncthreads();
        sm[tid] += u;
        __syncthreads();
    }
    if (tid < nb) boff[tid] = sm[tid] - v;
}

__launch_bounds__(256)
__global__ void k_scan3(const int* __restrict__ tmp, const int* __restrict__ boff,
                        const int* __restrict__ deg, int* __restrict__ ro,
                        int* __restrict__ cur)
{
    const int i = blockIdx.x * 256 + threadIdx.x;
    if (i < N_NODES) {
        int incl = tmp[i] + boff[i >> 8];
        ro[i + 1] = incl;
        cur[i] = incl - deg[i];
    }
    if (i == 0) ro[0] = 0;
}

__launch_bounds__(256)
__global__ void k_fill(const int* __restrict__ ei, int* __restrict__ cur,
                       int* __restrict__ csr)
{
    const int stride = gridDim.x * 256;
    for (int e = blockIdx.x * 256 + threadIdx.x; e < N_EDGES; e += stride) {
        const int dst = ei[N_EDGES + e];
        const int p = atomicAdd(cur + dst, 1);
        csr[p] = ei[e];
    }
}

// ---------------------------------------------------------------------------
// k_gather64: acc1[n] += sum over in-edges of t1(bf16)[src]; wave/node
// ---------------------------------------------------------------------------
__launch_bounds__(256)
__global__ void k_gather64(const int* __restrict__ ro, const int* __restrict__ csr,
                           const u16* __restrict__ t, float* __restrict__ acc)
{
    const int wid = (blockIdx.x << 2) | (threadIdx.x >> 6);
    if (wid >= N_NODES) return;
    const int lane = threadIdx.x & 63;
    const int s = ro[wid], e = ro[wid + 1];
    float a = acc[(size_t)wid * 64 + lane];
    int i = s;
    for (; i + 8 <= e; i += 8) {
        int s0 = csr[i], s1 = csr[i + 1], s2 = csr[i + 2], s3 = csr[i + 3];
        int s4 = csr[i + 4], s5 = csr[i + 5], s6 = csr[i + 6], s7 = csr[i + 7];
        u16 v0 = t[(size_t)s0 * 64 + lane], v1 = t[(size_t)s1 * 64 + lane];
        u16 v2 = t[(size_t)s2 * 64 + lane], v3 = t[(size_t)s3 * 64 + lane];
        u16 v4 = t[(size_t)s4 * 64 + lane], v5 = t[(size_t)s5 * 64 + lane];
        u16 v6 = t[(size_t)s6 * 64 + lane], v7 = t[(size_t)s7 * 64 + lane];
        a += bf2f(v0); a += bf2f(v1); a += bf2f(v2); a += bf2f(v3);
        a += bf2f(v4); a += bf2f(v5); a += bf2f(v6); a += bf2f(v7);
    }
    for (; i < e; ++i) a += bf2f(t[(size_t)csr[i] * 64 + lane]);
    acc[(size_t)wid * 64 + lane] = a;
}

// ---------------------------------------------------------------------------
// k_gpos: fused gather32 + lrelu + pos GEMV
// ---------------------------------------------------------------------------
__launch_bounds__(256)
__global__ void k_gpos(const int* __restrict__ ro, const int* __restrict__ csr,
                       const u16* __restrict__ t, const float* __restrict__ acc2,
                       const float* __restrict__ PW, const float* __restrict__ PB,
                       float* __restrict__ out)
{
    const int wid = (blockIdx.x << 2) | (threadIdx.x >> 6);
    if (wid >= N_NODES) return;
    const int lane = threadIdx.x & 63;
    const int half = lane >> 5, f = lane & 31;
    const int s = ro[wid], e = ro[wid + 1];
    float a = 0.f;
    int i = s;
    for (; i + 8 <= e; i += 8) {
        int s0 = csr[i + half], s1 = csr[i + 2 + half];
        int s2 = csr[i + 4 + half], s3 = csr[i + 6 + half];
        u16 v0 = t[(size_t)s0 * 32 + f], v1 = t[(size_t)s1 * 32 + f];
        u16 v2 = t[(size_t)s2 * 32 + f], v3 = t[(size_t)s3 * 32 + f];
        a += bf2f(v0); a += bf2f(v1); a += bf2f(v2); a += bf2f(v3);
    }
    for (; i < e; i += 2) {
        int idx = i + half;
        if (idx < e) a += bf2f(t[(size_t)csr[idx] * 32 + f]);
    }
    a += __shfl_xor(a, 32, 64);

    float v = lrelu(acc2[(size_t)wid * 32 + f] + a);
    float p0 = v * PW[f], p1 = v * PW[32 + f], p2 = v * PW[64 + f];
#pragma unroll
    for (int off = 16; off >= 1; off >>= 1) {
        p0 += __shfl_xor(p0, off, 64);
        p1 += __shfl_xor(p1, off, 64);
        p2 += __shfl_xor(p2, off, 64);
    }
    if (lane == 0) {
        out[(size_t)wid * 3 + 0] = p0 + PB[0];
        out[(size_t)wid * 3 + 1] = p1 + PB[1];
        out[(size_t)wid * 3 + 2] = p2 + PB[2];
    }
}

// ---------------------------------------------------------------------------
extern "C" void kernel_launch(void* const* d_in, const int* in_sizes, int n_in,
                              void* d_out, int out_size, void* d_ws, size_t ws_size,
                              hipStream_t stream)
{
    const float* x        = (const float*)d_in[0];
    const int*   ei       = (const int*)d_in[1];
    const float* lin1_w   = (const float*)d_in[2];
    const float* lin1_b   = (const float*)d_in[3];
    const float* c1_wrel  = (const float*)d_in[4];
    const float* c1_brel  = (const float*)d_in[5];
    const float* c1_wroot = (const float*)d_in[6];
    const float* c4_wrel  = (const float*)d_in[7];
    const float* c4_brel  = (const float*)d_in[8];
    const float* c4_wroot = (const float*)d_in[9];
    const float* pos_w    = (const float*)d_in[10];
    const float* pos_b    = (const float*)d_in[11];
    float* out = (float*)d_out;

    char* base = (char*)d_ws;
    u16*   t1b  = (u16*)base;                        // [N][64] bf16 = 6.4 MB
    float* acc1 = (float*)(base + 6400000);          // [N][64] f32  = 12.8 MB
    u16*   t2b  = (u16*)(base + 19200000);           // [N][32] bf16 = 3.2 MB
    float* acc2 = (float*)(base + 22400000);         // [N][32] f32  = 6.4 MB
    u16*   wf1  = (u16*)(base + 28800000);           // 512 KB
    u16*   wf2  = wf1 + 262144;                      // 32 KB
    u16*   wf3  = wf2 + 16384;                       // 8 KB
    int*   ibase = (int*)(wf3 + 4096);
    const int NPAD = ((N_NODES + 255) / 256) * 256;  // 50176
    int* deg  = ibase;
    int* tmp  = deg  + NPAD;
    int* ro   = tmp  + NPAD;
    int* cur  = ro   + NPAD;
    int* bsum = cur  + NPAD;
    int* boff = bsum + 256;
    int* csr  = boff + 256;
    const int NB = (N_NODES + 255) / 256;            // 196

    // weight tables + deg zero (one kernel), then CSR build
    hipLaunchKernelGGL(k_prep, dim3(1104 + NB), dim3(256), 0, stream,
                       lin1_w, c1_wrel, c1_wroot, c4_wrel, c4_wroot,
                       wf1, wf2, wf3, deg);
    hipLaunchKernelGGL(k_hist, dim3(1024), dim3(256), 0, stream, ei, deg);
    hipLaunchKernelGGL(k_scan1, dim3(NB), dim3(256), 0, stream, deg, tmp, bsum);
    hipLaunchKernelGGL(k_scan2p, dim3(1), dim3(256), 0, stream, bsum, boff, NB);
    hipLaunchKernelGGL(k_scan3, dim3(NB), dim3(256), 0, stream, tmp, boff, deg, ro, cur);
    hipLaunchKernelGGL(k_fill, dim3(1024), dim3(256), 0, stream, ei, cur, csr);

    // fused: h1(in-LDS) -> t1/acc1   (BM=64, 256 threads, 2-slot ping-pong)
    hipLaunchKernelGGL(k_linf, dim3((N_NODES + 63) / 64), dim3(256), 0, stream,
                       x, wf1, wf2, lin1_b, c1_brel, t1b, acc1);
    // acc1 += gather(t1)
    hipLaunchKernelGGL(k_gather64, dim3((N_NODES + 3) / 4), dim3(256), 0, stream,
                       ro, csr, t1b, acc1);
    // t2/acc2
    hipLaunchKernelGGL(k_dualf2, dim3((N_NODES + 63) / 64), dim3(256), 0, stream,
                       acc1, wf3, c4_brel, t2b, acc2);
    // out = lrelu(acc2 + gather(t2)) @ pos_w.T + pos_b
    hipLaunchKernelGGL(k_gpos, dim3((N_NODES + 3) / 4), dim3(256), 0, stream,
                       ro, csr, t2b, acc2, pos_w, pos_b, out);
}

// Round 16
// 361.337 us; speedup vs baseline: 1.3391x; 1.1422x over previous
//
#include <hip/hip_runtime.h>

#define N_NODES 50000
#define N_EDGES 1600000
#define LIN_BLOCKS 782
#define HIST_BLOCKS 1024

typedef __attribute__((ext_vector_type(4))) float f32x4;
typedef __attribute__((ext_vector_type(8))) short bf16x8;
typedef unsigned short u16;

__device__ __forceinline__ float lrelu(float x) { return x >= 0.f ? x : 0.01f * x; }

__device__ __forceinline__ u16 f2bf(float f) {
    union { float f; unsigned u; } v; v.f = f;
    unsigned u = v.u;
    u += 0x7fffu + ((u >> 16) & 1u);
    return (u16)(u >> 16);
}

__device__ __forceinline__ float bf2f(u16 v) {
    union { unsigned u; float f; } x; x.u = ((unsigned)v) << 16; return x.f;
}

__device__ __forceinline__ bf16x8 cvt8(float4 a, float4 b) {
    bf16x8 r;
    r[0] = (short)f2bf(a.x); r[1] = (short)f2bf(a.y);
    r[2] = (short)f2bf(a.z); r[3] = (short)f2bf(a.w);
    r[4] = (short)f2bf(b.x); r[5] = (short)f2bf(b.y);
    r[6] = (short)f2bf(b.z); r[7] = (short)f2bf(b.w);
    return r;
}

// ---------------------------------------------------------------------------
// k_prep: fragment-ordered bf16 weight tables + hist (deg pre-zeroed by
// hipMemsetAsync). Wf layout [kstep][nf][lane][8].
// ---------------------------------------------------------------------------
__launch_bounds__(256)
__global__ void k_prep(const float* __restrict__ W1,
                       const float* __restrict__ W2a, const float* __restrict__ W2b,
                       const float* __restrict__ W3a, const float* __restrict__ W3b,
                       u16* __restrict__ wf1, u16* __restrict__ wf2, u16* __restrict__ wf3,
                       const int* __restrict__ ei, int* __restrict__ deg)
{
    const int b = blockIdx.x;
    if (b < 1024) {
        int i = b * 256 + threadIdx.x;
        int e = i & 7, lane = (i >> 3) & 63, nf = (i >> 9) & 7, ks = i >> 12;
        int n = nf * 16 + (lane & 15);
        int k = ks * 32 + 8 * (lane >> 4) + e;
        wf1[i] = f2bf(W1[(size_t)n * 2048 + k]);
    } else if (b < 1088) {
        int i = (b - 1024) * 256 + threadIdx.x;
        int e = i & 7, lane = (i >> 3) & 63, nf = (i >> 9) & 7, ks = i >> 12;
        int n = nf * 16 + (lane & 15);
        int k = ks * 32 + 8 * (lane >> 4) + e;
        float v = (n < 64) ? W2a[(size_t)n * 128 + k] : W2b[(size_t)(n - 64) * 128 + k];
        wf2[i] = f2bf(v);
    } else if (b < 1104) {
        int i = (b - 1088) * 256 + threadIdx.x;
        int e = i & 7, lane = (i >> 3) & 63, nf = (i >> 9) & 3, ks = i >> 11;
        int n = nf * 16 + (lane & 15);
        int k = ks * 32 + 8 * (lane >> 4) + e;
        float v = (n < 32) ? W3a[(size_t)n * 64 + k] : W3b[(size_t)(n - 32) * 64 + k];
        wf3[i] = f2bf(v);
    } else {
        for (int e = (b - 1104) * 256 + threadIdx.x; e < N_EDGES; e += HIST_BLOCKS * 256)
            atomicAdd(deg + ei[N_EDGES + e], 1);
    }
}

// ---------------------------------------------------------------------------
// k_linf: FUSED  h1 = lrelu(x @ lin1_w.T + b) -> t1(bf16)/acc1(f32) ; +fill.
// EXACT 361.4-us configuration (Round-9 header kernel): BM=64, 256 threads,
// 2x2 wave layout, 2-slot ping-pong (slot 12KB = A 4KB bf16 + B 8KB),
// 2-stage reg lookahead, raw s_barrier + lgkmcnt only, (256,4), setprio,
// CSR-fill tail hidden in block retirement.
// ---------------------------------------------------------------------------
__device__ __forceinline__ void compute_step(const char* slot, int lane, int wave,
                                             f32x4 acc[2][4])
{
    const int lrow = lane & 15;
    const int k16 = lane >> 4;
    const int rs = wave >> 1;                    // row strip (32 rows)
    const int ch = wave & 1;                     // col half (nf base ch*4)

    bf16x8 af[2];
#pragma unroll
    for (int st = 0; st < 2; st++) {
        const int row = rs * 32 + st * 16 + lrow;
        af[st] = *(const bf16x8*)(slot + row * 64 + ((k16 ^ (row & 3)) << 4));
    }
    bf16x8 bf[4];
#pragma unroll
    for (int j = 0; j < 4; j++)
        bf[j] = *(const bf16x8*)(slot + 4096 + (ch * 4 + j) * 1024 + lane * 16);

    __builtin_amdgcn_s_setprio(1);
#pragma unroll
    for (int st = 0; st < 2; st++)
#pragma unroll
        for (int j = 0; j < 4; j++)
            acc[st][j] = __builtin_amdgcn_mfma_f32_16x16x32_bf16(af[st], bf[j], acc[st][j], 0, 0, 0);
    __builtin_amdgcn_s_setprio(0);
}

__launch_bounds__(256, 4)
__global__ void k_linf(const float* __restrict__ X, const u16* __restrict__ Wf1,
                       const u16* __restrict__ Wf2,
                       const float* __restrict__ Bv, const float* __restrict__ brel,
                       u16* __restrict__ t1, float* __restrict__ acc1,
                       const int* __restrict__ ei, int* __restrict__ cur,
                       int* __restrict__ csr)
{
    __shared__ __align__(16) char lds[2][12288];

    const int t = threadIdx.x, wave = t >> 6, lane = t & 63;
    const int lrow = lane & 15, lgrp = lane >> 4;
    const int m0 = blockIdx.x * 64;

    // staging geometry: thread t stages row=t>>2, k-chunk kq=t&3 (8 elems)
    const int arow_l = t >> 2, kq = t & 3;
    int grow = m0 + arow_l; if (grow >= N_NODES) grow = N_NODES - 1;
    const float4* ap = (const float4*)(X + (size_t)grow * 2048);   // + s*8 + kq*2
    const bf16x8* bp = (const bf16x8*)Wf1;                          // + s*512 + t*2
    const int awr = arow_l * 64 + ((kq ^ (arow_l & 3)) << 4);
    const int bwr = 4096 + t * 32;

    f32x4 acc[2][4];
#pragma unroll
    for (int st = 0; st < 2; st++)
#pragma unroll
        for (int j = 0; j < 4; j++) acc[st][j] = (f32x4)0.f;

    // prologue: s=0 (c), s=1 (n); write s=0 into slot0
    float4 cA0 = ap[kq * 2], cA1 = ap[kq * 2 + 1];
    bf16x8 cB0 = bp[t * 2], cB1 = bp[t * 2 + 1];
    float4 nA0 = ap[8 + kq * 2], nA1 = ap[8 + kq * 2 + 1];
    bf16x8 nB0 = bp[512 + t * 2], nB1 = bp[512 + t * 2 + 1];
    *(bf16x8*)(lds[0] + awr) = cvt8(cA0, cA1);
    *(bf16x8*)(lds[0] + bwr) = cB0;
    *(bf16x8*)(lds[0] + bwr + 16) = cB1;
    asm volatile("s_waitcnt lgkmcnt(0)" ::: "memory");
    __builtin_amdgcn_s_barrier();
    __builtin_amdgcn_sched_barrier(0);

#pragma unroll 2
    for (int s = 0; s < 62; s++) {
        // issue loads for stage s+2 (stay in flight across compute+write)
        float4 fA0 = ap[(s + 2) * 8 + kq * 2], fA1 = ap[(s + 2) * 8 + kq * 2 + 1];
        bf16x8 fB0 = bp[(s + 2) * 512 + t * 2], fB1 = bp[(s + 2) * 512 + t * 2 + 1];

        compute_step(lds[s & 1], lane, wave, acc);
        __builtin_amdgcn_s_barrier();                 // all waves done reading slot s&1
        __builtin_amdgcn_sched_barrier(0);

        char* wslot = lds[(s + 1) & 1];
        *(bf16x8*)(wslot + awr) = cvt8(nA0, nA1);
        *(bf16x8*)(wslot + bwr) = nB0;
        *(bf16x8*)(wslot + bwr + 16) = nB1;
        asm volatile("s_waitcnt lgkmcnt(0)" ::: "memory");
        __builtin_amdgcn_s_barrier();                 // slot (s+1)&1 now readable
        __builtin_amdgcn_sched_barrier(0);

        nA0 = fA0; nA1 = fA1; nB0 = fB0; nB1 = fB1;
    }
    // peeled tail: s=62 (write s=63), s=63
    compute_step(lds[0], lane, wave, acc);
    __builtin_amdgcn_s_barrier();
    __builtin_amdgcn_sched_barrier(0);
    *(bf16x8*)(lds[1] + awr) = cvt8(nA0, nA1);
    *(bf16x8*)(lds[1] + bwr) = nB0;
    *(bf16x8*)(lds[1] + bwr + 16) = nB1;
    asm volatile("s_waitcnt lgkmcnt(0)" ::: "memory");
    __builtin_amdgcn_s_barrier();
    __builtin_amdgcn_sched_barrier(0);
    compute_step(lds[1], lane, wave, acc);
    __builtin_amdgcn_s_barrier();     // slots dead after this; hl overlays lds
    __builtin_amdgcn_sched_barrier(0);

    // ---- fused dual GEMM epilogue ----
    u16* hl = (u16*)&lds[0][0];
    {
        const int rs = wave >> 1, ch = wave & 1;
#pragma unroll
        for (int st = 0; st < 2; st++) {
#pragma unroll
            for (int j = 0; j < 4; j++) {
                const int col = ch * 64 + j * 16 + lrow;
                const float bias = Bv[col];
#pragma unroll
                for (int r = 0; r < 4; r++) {
                    const int row = rs * 32 + st * 16 + lgrp * 4 + r;
                    hl[row * 128 + (((col >> 3) ^ (row & 7)) << 3) + (col & 7)] =
                        f2bf(lrelu(acc[st][j][r] + bias));
                }
            }
        }
    }
    asm volatile("s_waitcnt lgkmcnt(0)" ::: "memory");
    __builtin_amdgcn_s_barrier();
    __builtin_amdgcn_sched_barrier(0);

    // dual GEMM: wave handles rows wave*16..+16, all 8 nf (K=128)
    bf16x8 af2[4];
    {
        const int row = wave * 16 + lrow;
#pragma unroll
        for (int ks = 0; ks < 4; ks++) {
            const int chunk = ((ks << 2) + lgrp) ^ (row & 7);
            af2[ks] = *(const bf16x8*)(hl + row * 128 + (chunk << 3));
        }
    }
    f32x4 dacc[8];
#pragma unroll
    for (int i = 0; i < 8; i++) dacc[i] = (f32x4)0.f;
    const u16* bp2 = Wf2 + lane * 8;
#pragma unroll
    for (int ks = 0; ks < 4; ks++) {
#pragma unroll
        for (int nf = 0; nf < 8; nf++) {
            bf16x8 bf = *(const bf16x8*)(bp2 + ks * 4096 + nf * 512);
            dacc[nf] = __builtin_amdgcn_mfma_f32_16x16x32_bf16(af2[ks], bf, dacc[nf], 0, 0, 0);
        }
    }

    const int rbase = m0 + wave * 16 + lgrp * 4;
#pragma unroll
    for (int nf = 0; nf < 8; nf++) {
        const int col = nf * 16 + lrow;
#pragma unroll
        for (int r = 0; r < 4; r++) {
            const int row = rbase + r;
            if (row < N_NODES) {
                if (col < 64) t1[(size_t)row * 64 + col] = f2bf(dacc[nf][r]);
                else          acc1[(size_t)row * 64 + (col - 64)] = dacc[nf][r] + brel[col - 64];
            }
        }
    }

    // ---- CSR fill tail (hidden in block-retirement tail) ----
    for (int e = blockIdx.x * 256 + t; e < N_EDGES; e += LIN_BLOCKS * 256) {
        const int dst = ei[N_EDGES + e];
        const int p = atomicAdd(cur + dst, 1);
        csr[p] = ei[e];
    }
}

// ---------------------------------------------------------------------------
// k_dualf2: t2(bf16)/acc2(f32) from lrelu(acc1)  (K=64, N=64)
// ---------------------------------------------------------------------------
__launch_bounds__(256, 2)
__global__ void k_dualf2(const float* __restrict__ A, const u16* __restrict__ Wf,
                         const float* __restrict__ brel,
                         u16* __restrict__ t2, float* __restrict__ acc2)
{
    const int t = threadIdx.x, wave = t >> 6, lane = t & 63;
    const int lrow = lane & 15, lgrp = lane >> 4;
    const int arow = blockIdx.x * 64 + wave * 16 + lrow;
    const float* ap = A + (size_t)(arow < N_NODES ? arow : 0) * 64 + 8 * lgrp;
    const u16* bp = Wf + lane * 8;

    float4 a00 = *(const float4*)(ap + 0);
    float4 a01 = *(const float4*)(ap + 4);
    float4 a10 = *(const float4*)(ap + 32);
    float4 a11 = *(const float4*)(ap + 36);

    f32x4 acc[4];
#pragma unroll
    for (int i = 0; i < 4; i++) acc[i] = (f32x4)0.f;

    a00.x = lrelu(a00.x); a00.y = lrelu(a00.y); a00.z = lrelu(a00.z); a00.w = lrelu(a00.w);
    a01.x = lrelu(a01.x); a01.y = lrelu(a01.y); a01.z = lrelu(a01.z); a01.w = lrelu(a01.w);
    bf16x8 af0 = cvt8(a00, a01);
    a10.x = lrelu(a10.x); a10.y = lrelu(a10.y); a10.z = lrelu(a10.z); a10.w = lrelu(a10.w);
    a11.x = lrelu(a11.x); a11.y = lrelu(a11.y); a11.z = lrelu(a11.z); a11.w = lrelu(a11.w);
    bf16x8 af1 = cvt8(a10, a11);

#pragma unroll
    for (int nf = 0; nf < 4; nf++) {
        bf16x8 b0 = *(const bf16x8*)(bp + nf * 512);
        bf16x8 b1 = *(const bf16x8*)(bp + 2048 + nf * 512);
        acc[nf] = __builtin_amdgcn_mfma_f32_16x16x32_bf16(af0, b0, acc[nf], 0, 0, 0);
        acc[nf] = __builtin_amdgcn_mfma_f32_16x16x32_bf16(af1, b1, acc[nf], 0, 0, 0);
    }

    const int rbase = blockIdx.x * 64 + wave * 16 + lgrp * 4;
#pragma unroll
    for (int nf = 0; nf < 4; nf++) {
        const int col = nf * 16 + lrow;
#pragma unroll
        for (int r = 0; r < 4; r++) {
            const int row = rbase + r;
            if (row < N_NODES) {
                if (col < 32) t2[(size_t)row * 32 + col] = f2bf(acc[nf][r]);
                else          acc2[(size_t)row * 32 + (col - 32)] = acc[nf][r] + brel[col - 32];
            }
        }
    }
}

// ---------------------------------------------------------------------------
// scans (CSR offsets)
// ---------------------------------------------------------------------------
__launch_bounds__(256)
__global__ void k_scan1(const int* __restrict__ deg, int* __restrict__ tmp,
                        int* __restrict__ bsum)
{
    __shared__ int sm[256];
    const int tid = threadIdx.x;
    const int i = blockIdx.x * 256 + tid;
    int d = (i < N_NODES) ? deg[i] : 0;
    sm[tid] = d;
    __syncthreads();
#pragma unroll
    for (int off = 1; off < 256; off <<= 1) {
        int v = (tid >= off) ? sm[tid - off] : 0;
        __syncthreads();
        sm[tid] += v;
        __syncthreads();
    }
    if (i < N_NODES) tmp[i] = sm[tid];
    if (tid == 255) bsum[blockIdx.x] = sm[255];
}

__launch_bounds__(256)
__global__ void k_scan2p(const int* __restrict__ bsum, int* __restrict__ boff, int nb)
{
    __shared__ int sm[256];
    const int tid = threadIdx.x;
    int v = (tid < nb) ? bsum[tid] : 0;
    sm[tid] = v;
    __syncthreads();
#pragma unroll
    for (int off = 1; off < 256; off <<= 1) {
        int u = (tid >= off) ? sm[tid - off] : 0;
        __syncthreads();
        sm[tid] += u;
        __syncthreads();
    }
    if (tid < nb) boff[tid] = sm[tid] - v;
}

__launch_bounds__(256)
__global__ void k_scan3(const int* __restrict__ tmp, const int* __restrict__ boff,
                        const int* __restrict__ deg, int* __restrict__ ro,
                        int* __restrict__ cur)
{
    const int i = blockIdx.x * 256 + threadIdx.x;
    if (i < N_NODES) {
        int incl = tmp[i] + boff[i >> 8];
        ro[i + 1] = incl;
        cur[i] = incl - deg[i];
    }
    if (i == 0) ro[0] = 0;
}

// ---------------------------------------------------------------------------
// k_gather64: acc1[n] += sum over in-edges of t1(bf16)[src]; wave/node
// ---------------------------------------------------------------------------
__launch_bounds__(256)
__global__ void k_gather64(const int* __restrict__ ro, const int* __restrict__ csr,
                           const u16* __restrict__ t, float* __restrict__ acc)
{
    const int wid = (blockIdx.x << 2) | (threadIdx.x >> 6);
    if (wid >= N_NODES) return;
    const int lane = threadIdx.x & 63;
    const int s = ro[wid], e = ro[wid + 1];
    float a = acc[(size_t)wid * 64 + lane];
    int i = s;
    for (; i + 8 <= e; i += 8) {
        int s0 = csr[i], s1 = csr[i + 1], s2 = csr[i + 2], s3 = csr[i + 3];
        int s4 = csr[i + 4], s5 = csr[i + 5], s6 = csr[i + 6], s7 = csr[i + 7];
        u16 v0 = t[(size_t)s0 * 64 + lane], v1 = t[(size_t)s1 * 64 + lane];
        u16 v2 = t[(size_t)s2 * 64 + lane], v3 = t[(size_t)s3 * 64 + lane];
        u16 v4 = t[(size_t)s4 * 64 + lane], v5 = t[(size_t)s5 * 64 + lane];
        u16 v6 = t[(size_t)s6 * 64 + lane], v7 = t[(size_t)s7 * 64 + lane];
        a += bf2f(v0); a += bf2f(v1); a += bf2f(v2); a += bf2f(v3);
        a += bf2f(v4); a += bf2f(v5); a += bf2f(v6); a += bf2f(v7);
    }
    for (; i < e; ++i) a += bf2f(t[(size_t)csr[i] * 64 + lane]);
    acc[(size_t)wid * 64 + lane] = a;
}

// ---------------------------------------------------------------------------
// k_gpos: fused gather32 + lrelu + pos GEMV
// ---------------------------------------------------------------------------
__launch_bounds__(256)
__global__ void k_gpos(const int* __restrict__ ro, const int* __restrict__ csr,
                       const u16* __restrict__ t, const float* __restrict__ acc2,
                       const float* __restrict__ PW, const float* __restrict__ PB,
                       float* __restrict__ out)
{
    const int wid = (blockIdx.x << 2) | (threadIdx.x >> 6);
    if (wid >= N_NODES) return;
    const int lane = threadIdx.x & 63;
    const int half = lane >> 5, f = lane & 31;
    const int s = ro[wid], e = ro[wid + 1];
    float a = 0.f;
    int i = s;
    for (; i + 8 <= e; i += 8) {
        int s0 = csr[i + half], s1 = csr[i + 2 + half];
        int s2 = csr[i + 4 + half], s3 = csr[i + 6 + half];
        u16 v0 = t[(size_t)s0 * 32 + f], v1 = t[(size_t)s1 * 32 + f];
        u16 v2 = t[(size_t)s2 * 32 + f], v3 = t[(size_t)s3 * 32 + f];
        a += bf2f(v0); a += bf2f(v1); a += bf2f(v2); a += bf2f(v3);
    }
    for (; i < e; i += 2) {
        int idx = i + half;
        if (idx < e) a += bf2f(t[(size_t)csr[idx] * 32 + f]);
    }
    a += __shfl_xor(a, 32, 64);

    float v = lrelu(acc2[(size_t)wid * 32 + f] + a);
    float p0 = v * PW[f], p1 = v * PW[32 + f], p2 = v * PW[64 + f];
#pragma unroll
    for (int off = 16; off >= 1; off >>= 1) {
        p0 += __shfl_xor(p0, off, 64);
        p1 += __shfl_xor(p1, off, 64);
        p2 += __shfl_xor(p2, off, 64);
    }
    if (lane == 0) {
        out[(size_t)wid * 3 + 0] = p0 + PB[0];
        out[(size_t)wid * 3 + 1] = p1 + PB[1];
        out[(size_t)wid * 3 + 2] = p2 + PB[2];
    }
}

// ---------------------------------------------------------------------------
extern "C" void kernel_launch(void* const* d_in, const int* in_sizes, int n_in,
                              void* d_out, int out_size, void* d_ws, size_t ws_size,
                              hipStream_t stream)
{
    const float* x        = (const float*)d_in[0];
    const int*   ei       = (const int*)d_in[1];
    const float* lin1_w   = (const float*)d_in[2];
    const float* lin1_b   = (const float*)d_in[3];
    const float* c1_wrel  = (const float*)d_in[4];
    const float* c1_brel  = (const float*)d_in[5];
    const float* c1_wroot = (const float*)d_in[6];
    const float* c4_wrel  = (const float*)d_in[7];
    const float* c4_brel  = (const float*)d_in[8];
    const float* c4_wroot = (const float*)d_in[9];
    const float* pos_w    = (const float*)d_in[10];
    const float* pos_b    = (const float*)d_in[11];
    float* out = (float*)d_out;

    char* base = (char*)d_ws;
    u16*   t1b  = (u16*)base;                        // [N][64] bf16 = 6.4 MB
    float* acc1 = (float*)(base + 6400000);          // [N][64] f32  = 12.8 MB
    u16*   t2b  = (u16*)(base + 19200000);           // [N][32] bf16 = 3.2 MB
    float* acc2 = (float*)(base + 22400000);         // [N][32] f32  = 6.4 MB
    u16*   wf1  = (u16*)(base + 28800000);           // 512 KB
    u16*   wf2  = wf1 + 262144;                      // 32 KB
    u16*   wf3  = wf2 + 16384;                       // 8 KB
    int*   ibase = (int*)(wf3 + 4096);
    const int NPAD = ((N_NODES + 255) / 256) * 256;  // 50176
    int* deg  = ibase;
    int* tmp  = deg  + NPAD;
    int* ro   = tmp  + NPAD;
    int* cur  = ro   + NPAD;
    int* bsum = cur  + NPAD;
    int* boff = bsum + 256;
    int* csr  = boff + 256;
    const int NB = (N_NODES + 255) / 256;            // 196

    // deg = 0, then tables + hist together
    hipMemsetAsync(deg, 0, (size_t)NPAD * sizeof(int), stream);
    hipLaunchKernelGGL(k_prep, dim3(1104 + HIST_BLOCKS), dim3(256), 0, stream,
                       lin1_w, c1_wrel, c1_wroot, c4_wrel, c4_wroot,
                       wf1, wf2, wf3, ei, deg);
    hipLaunchKernelGGL(k_scan1, dim3(NB), dim3(256), 0, stream, deg, tmp, bsum);
    hipLaunchKernelGGL(k_scan2p, dim3(1), dim3(256), 0, stream, bsum, boff, NB);
    hipLaunchKernelGGL(k_scan3, dim3(NB), dim3(256), 0, stream, tmp, boff, deg, ro, cur);

    // fused: h1(in-LDS) -> t1/acc1 ; + CSR fill tail
    hipLaunchKernelGGL(k_linf, dim3(LIN_BLOCKS), dim3(256), 0, stream,
                       x, wf1, wf2, lin1_b, c1_brel, t1b, acc1, ei, cur, csr);
    // acc1 += gather(t1)
    hipLaunchKernelGGL(k_gather64, dim3((N_NODES + 3) / 4), dim3(256), 0, stream,
                       ro, csr, t1b, acc1);
    // t2/acc2
    hipLaunchKernelGGL(k_dualf2, dim3((N_NODES + 63) / 64), dim3(256), 0, stream,
                       acc1, wf3, c4_brel, t2b, acc2);
    // out = lrelu(acc2 + gather(t2)) @ pos_w.T + pos_b
    hipLaunchKernelGGL(k_gpos, dim3((N_NODES + 3) / 4), dim3(256), 0, stream,
                       ro, csr, t2b, acc2, pos_w, pos_b, out);
}